// Round 3
// baseline (394.126 us; speedup 1.0000x reference)
//
#include <hip/hip_runtime.h>
#include <hip/hip_bf16.h>
#include <math.h>

// Problem constants: N=524288, F=128, C=32, EPS=10.0
#define NS 524288
#define FDIM 128
#define CDIM 32
#define EPSV 10.0f

typedef __attribute__((ext_vector_type(8))) short short8;
typedef __attribute__((ext_vector_type(16))) float float16v;

// ws layout (float indices):
//   [0, 4096)    : Bpk bf16[32][256]  -- Bpk[c][2f]=bf16(a_cf), Bpk[c][2f+1]=bf16(-b_cf)
//   [4096, 4128) : d[c] = sum_f mean^2 * a
//   [4128, 4160) : L[c] = sum_f log(sig)
#define WS_D 4096
#define WS_L 4128

static __device__ __forceinline__ short f2bf(float x) {
    __hip_bfloat16 h = __float2bfloat16(x);   // RN
    return __builtin_bit_cast(short, h);
}

static __device__ __forceinline__ short8 make_afrag(float4 v) {
    // packed-K interleave: even k -> ft^2 (pairs with a), odd k -> ft (pairs with -b)
    short8 r;
    r[0] = f2bf(v.x * v.x); r[1] = f2bf(v.x);
    r[2] = f2bf(v.y * v.y); r[3] = f2bf(v.y);
    r[4] = f2bf(v.z * v.z); r[5] = f2bf(v.z);
    r[6] = f2bf(v.w * v.w); r[7] = f2bf(v.w);
    return r;
}

__global__ void precomp_kernel(const float* __restrict__ mean,
                               const float* __restrict__ sigma,
                               float* __restrict__ ws) {
    int c = blockIdx.x;   // 32 blocks
    int f = threadIdx.x;  // 128 threads
    float sg  = sigma[c * FDIM + f] + EPSV;
    float m   = mean[c * FDIM + f];
    float inv = 1.0f / (sg * sg);
    float a   = 0.5f * inv;
    float b   = m * inv;
    unsigned ha = (unsigned short)f2bf(a);
    unsigned hb = (unsigned short)f2bf(-b);
    ((unsigned*)ws)[c * FDIM + f] = ha | (hb << 16);

    float dpart = m * m * a;
    float lpart = __logf(sg);
    for (int off = 32; off; off >>= 1) {
        dpart += __shfl_down(dpart, off);
        lpart += __shfl_down(lpart, off);
    }
    __shared__ float sd[2], sl[2];
    int wv = f >> 6;
    if ((f & 63) == 0) { sd[wv] = dpart; sl[wv] = lpart; }
    __syncthreads();
    if (f == 0) {
        ws[WS_D + c] = sd[0] + sd[1];
        ws[WS_L + c] = sl[0] + sl[1];
    }
}

__launch_bounds__(256)
__global__ void gmm_main_kernel(const float* __restrict__ ft,
                                const int* __restrict__ ygt,
                                const float* __restrict__ cp,
                                const float* __restrict__ ws,
                                float* __restrict__ out) {
    // Q (epilogue quad values, stride 33) aliases the A-staging buffer:
    // A needs 256 rows x 32 floats x (sq,val) bf16 = 32768 B <= 33792 B.
    __shared__ float Q[256 * 33];
    __shared__ float Wp[32 * 33];
    __shared__ float red[4];
    short8* Aunits = (short8*)Q;

    const int tid  = threadIdx.x;
    const int lane = tid & 63;
    const int w    = tid >> 6;          // wave 0..3
    const long long bs = (long long)blockIdx.x * 256;

    // W table: W[ci][o] = (ci!=o) * exp(L[ci]-L[o]) * p[o]/p[ci]
    for (int idx = tid; idx < 1024; idx += 256) {
        int ci = idx >> 5, o = idx & 31;
        float v = 0.0f;
        if (ci != o) v = __expf(ws[WS_L + ci] - ws[WS_L + o]) * cp[o] / cp[ci];
        Wp[ci * 33 + o] = v;
    }

    const int m  = lane & 31;   // MFMA row (sample sub-row) / B class row
    const int kg = lane >> 5;   // k half

    float16v acc0 = {};
    float16v acc1 = {};

    const short8* __restrict__ Bp = (const short8*)ws;
    const int bbase = m * 32;   // + ch*8 + s*2 + kg

    // Staging indices: thread covers rows r = (tid>>3) + it*32, unit u = tid&7
    const int r0 = tid >> 3, u = tid & 7;
    // A-unit byte address: region(r>>5)*4096 + (u>>1)*1024 + (u&1)*512 + (r&31)*16
    const int ubase = ((u >> 1) << 10) + ((u & 1) << 9);
    // Frag read base for this wave/lane: (w*2+mt)*4096 + s*1024 + kg*512 + m*16
    const int fr_base = (w << 13) + (kg << 9) + (m << 4);   // bytes; +s*1024; mt adds 4096

    for (int ch = 0; ch < 4; ++ch) {
        __syncthreads();  // prior chunk's frag reads done (covers Wp writes on ch=0)
        // Stage: coalesced global read (8 lanes = one 128B line), cvt to bf16 pairs,
        // transpose via LDS write addressing.
        #pragma unroll
        for (int it = 0; it < 8; ++it) {
            int r = r0 + it * 32;
            float4 v = *(const float4*)(ft + (bs + r) * FDIM + ch * 32 + u * 4);
            int baddr = ((r >> 5) << 12) + ubase + ((r & 31) << 4);
            Aunits[baddr >> 4] = make_afrag(v);
        }
        __syncthreads();

        // 4 k-steps of 16 packed-k each; A frags are contiguous 1024B wave reads
        #pragma unroll
        for (int s = 0; s < 4; ++s) {
            int ai = (fr_base + (s << 10)) >> 4;
            short8 a0 = Aunits[ai];
            short8 a1 = Aunits[ai + 256];   // mt=1: +4096B
            short8 bf = Bp[bbase + ch * 8 + s * 2 + kg];
            acc0 = __builtin_amdgcn_mfma_f32_32x32x16_bf16(a0, bf, acc0, 0, 0, 0);
            acc1 = __builtin_amdgcn_mfma_f32_32x32x16_bf16(a1, bf, acc1, 0, 0, 0);
        }
    }

    __syncthreads();   // all A reads done; safe to overwrite with Q

    // C/D layout (32x32): col = lane&31, row = (reg&3) + 8*(reg>>2) + 4*(lane>>5)
    #pragma unroll
    for (int r = 0; r < 16; ++r) {
        int row = (r & 3) + 8 * (r >> 2) + 4 * kg;
        Q[(w * 64 + row) * 33 + m]      = acc0[r];
        Q[(w * 64 + 32 + row) * 33 + m] = acc1[r];
    }
    __syncthreads();

    // Epilogue: thread t owns sample row t of the block
    const int ci = ygt[bs + tid];
    float q[CDIM];
    float qb = 0.0f;
    #pragma unroll
    for (int c = 0; c < CDIM; ++c) {
        float qq = Q[tid * 33 + c] + ws[WS_D + c];
        q[c] = qq;
        qb = (c == ci) ? qq : qb;
    }
    float outv = 0.0f;
    #pragma unroll
    for (int c = 0; c < CDIM; ++c) {
        outv += __expf(qb - q[c]) * Wp[ci * 33 + c];
    }
    float val = __logf(1.0f + outv) * (1.0f / (float)NS);

    for (int off = 32; off; off >>= 1) val += __shfl_down(val, off);
    if (lane == 0) red[w] = val;
    __syncthreads();
    if (tid == 0) atomicAdd(out, red[0] + red[1] + red[2] + red[3]);
}

extern "C" void kernel_launch(void* const* d_in, const int* in_sizes, int n_in,
                              void* d_out, int out_size, void* d_ws, size_t ws_size,
                              hipStream_t stream) {
    const float* ft    = (const float*)d_in[0];
    const float* mean  = (const float*)d_in[1];
    const float* sigma = (const float*)d_in[2];
    const float* cp    = (const float*)d_in[3];
    const int*   ygt   = (const int*)d_in[4];
    float* ws = (float*)d_ws;

    hipMemsetAsync(d_out, 0, sizeof(float), stream);
    precomp_kernel<<<32, 128, 0, stream>>>(mean, sigma, ws);
    gmm_main_kernel<<<NS / 256, 256, 0, stream>>>(ft, ygt, cp, ws, (float*)d_out);
}

// Round 4
// 367.011 us; speedup vs baseline: 1.0739x; 1.0739x over previous
//
#include <hip/hip_runtime.h>
#include <hip/hip_bf16.h>
#include <math.h>

// Problem constants: N=524288, F=128, C=32, EPS=10.0
#define NS 524288
#define FDIM 128
#define CDIM 32
#define EPSV 10.0f

typedef __attribute__((ext_vector_type(8))) short short8;
typedef __attribute__((ext_vector_type(16))) float float16v;

// ws float-index layout:
// [0,4096)    : class table bf16, t-major. 16B unit (t,c) at unit index t*32+c,
//               t = f>>2 in [0,32). Unit dword j (=f&3) = (bf16(a) | bf16(-b)<<16)
//               for f = t*4+j, a = 1/(2*sig^2), b = mean/sig^2.
// [4096,4128) : d[c] = sum_f mean^2 * a
// [4128,4160) : L[c] = sum_f log(sig)
#define WS_D 4096
#define WS_L 4128

static __device__ __forceinline__ short f2bf(float x) {
    __hip_bfloat16 h = __float2bfloat16(x);   // RN
    return __builtin_bit_cast(short, h);
}

static __device__ __forceinline__ short8 make_afrag(float4 v) {
    // packed-K interleave: even k -> ft^2 (pairs with a), odd k -> ft (pairs with -b)
    short8 r;
    r[0] = f2bf(v.x * v.x); r[1] = f2bf(v.x);
    r[2] = f2bf(v.y * v.y); r[3] = f2bf(v.y);
    r[4] = f2bf(v.z * v.z); r[5] = f2bf(v.z);
    r[6] = f2bf(v.w * v.w); r[7] = f2bf(v.w);
    return r;
}

__global__ void precomp_kernel(const float* __restrict__ mean,
                               const float* __restrict__ sigma,
                               float* __restrict__ ws) {
    int c = blockIdx.x;   // 32 blocks
    int f = threadIdx.x;  // 128 threads
    float sg  = sigma[c * FDIM + f] + EPSV;
    float m   = mean[c * FDIM + f];
    float inv = 1.0f / (sg * sg);
    float a   = 0.5f * inv;
    float b   = m * inv;
    unsigned ha = (unsigned short)f2bf(a);
    unsigned hb = (unsigned short)f2bf(-b);
    // t-major: unit (t=f>>2)*32 + c, dword j = f&3
    ((unsigned*)ws)[(((f >> 2) * 32 + c) << 2) + (f & 3)] = ha | (hb << 16);

    float dpart = m * m * a;
    float lpart = __logf(sg);
    for (int off = 32; off; off >>= 1) {
        dpart += __shfl_down(dpart, off);
        lpart += __shfl_down(lpart, off);
    }
    __shared__ float sd[2], sl[2];
    int wv = f >> 6;
    if ((f & 63) == 0) { sd[wv] = dpart; sl[wv] = lpart; }
    __syncthreads();
    if (f == 0) {
        ws[WS_D + c] = sd[0] + sd[1];
        ws[WS_L + c] = sl[0] + sl[1];
    }
}

__launch_bounds__(256)
__global__ void gmm_main_kernel(const float* __restrict__ ft,
                                const int* __restrict__ ygt,
                                const float* __restrict__ cp,
                                const float* __restrict__ ws,
                                float* __restrict__ out) {
    __shared__ short8 Abuf[2048];   // double-buffered sample staging, 2 x 16 KB
    __shared__ float  Wp[1024];     // W2[ci][o] = W[ci][o]*exp(d[ci]-d[o]), stride 32
    __shared__ float  red[4];

    const int tid  = threadIdx.x;
    const int lane = tid & 63;
    const int w    = tid >> 6;      // wave 0..3
    const int n    = lane & 31;     // MFMA col (sample) / A-row (class)
    const int kg   = lane >> 5;     // k half
    const long long bs = (long long)blockIdx.x * 256;

    // ---- prefetch chunk 0 of ft (BK=16 floats) ----
    const int r0 = tid >> 2;        // row base [0,64)
    const int q  = tid & 3;         // f-quad within chunk
    const float* ftb = ft + bs * FDIM + q * 4;
    float4 v[4];
    #pragma unroll
    for (int it = 0; it < 4; ++it)
        v[it] = *(const float4*)(ftb + (it * 64 + r0) * FDIM);

    // ---- W2 table (d folded in) ----
    for (int idx = tid; idx < 1024; idx += 256) {
        int ci = idx >> 5, o = idx & 31;
        float val = 0.0f;
        if (ci != o)
            val = __expf(ws[WS_L + ci] - ws[WS_L + o] + ws[WS_D + ci] - ws[WS_D + o])
                  * cp[o] / cp[ci];
        Wp[idx] = val;
    }
    __syncthreads();

    float16v acc0 = {}, acc1 = {};
    const short8* __restrict__ Bg = (const short8*)ws;  // class units, t-major

    const int wr_q  = q * 32;                     // + (r>>5)*128 + (r&31)
    const int rd0   = (w * 2) * 128 + kg * 32 + n;  // mt=0 read unit; +128 for mt=1; +64*s2

    for (int ch = 0; ch < 8; ++ch) {
        short8* ab = &Abuf[(ch & 1) << 10];
        // convert regs -> staged units (needs vmcnt wait, natural data dep)
        #pragma unroll
        for (int it = 0; it < 4; ++it) {
            int r = it * 64 + r0;
            ab[((r >> 5) << 7) + wr_q + (r & 31)] = make_afrag(v[it]);
        }
        __syncthreads();   // writes to buf[ch&1] visible; zero outstanding globals here
        // issue next chunk's loads AFTER the barrier (latency hidden by MFMA phase)
        if (ch < 7) {
            const float* p = ftb + (ch + 1) * 16;
            #pragma unroll
            for (int it = 0; it < 4; ++it)
                v[it] = *(const float4*)(p + (it * 64 + r0) * FDIM);
        }
        // MFMA phase: 2 k-steps, 2 sample tiles; class frags = contiguous coalesced
        // 1KB wave reads from global (L1/L2-hot, shared across all blocks)
        #pragma unroll
        for (int s2 = 0; s2 < 2; ++s2) {
            short8 cf = Bg[(ch * 4 + s2 * 2 + kg) * 32 + n];
            short8 sf0 = ab[rd0 + s2 * 64];
            short8 sf1 = ab[rd0 + 128 + s2 * 64];
            acc0 = __builtin_amdgcn_mfma_f32_32x32x16_bf16(cf, sf0, acc0, 0, 0, 0);
            acc1 = __builtin_amdgcn_mfma_f32_32x32x16_bf16(cf, sf1, acc1, 0, 0, 0);
        }
    }

    // ---- epilogue, in-register ----
    // D[class][sample]: lane holds sample n (tile0->acc0: row w*64+n; tile1->acc1:
    // +32), classes cr = (r&3)+8*(r>>2)+4*kg (16 of 32; partner lane^32 has rest).
    const int ci0 = ygt[bs + w * 64 + n];
    const int ci1 = ygt[bs + w * 64 + 32 + n];
    float P0 = 0.0f, P1 = 0.0f, qb0 = 0.0f, qb1 = 0.0f;
    #pragma unroll
    for (int r = 0; r < 16; ++r) {
        int cr = (r & 3) + 8 * (r >> 2) + 4 * kg;
        float q0 = acc0[r];
        float q1 = acc1[r];
        P0 += __expf(-q0) * Wp[ci0 * 32 + cr];   // diagonal W=0 handles cr==ci
        P1 += __expf(-q1) * Wp[ci1 * 32 + cr];
        qb0 = (cr == ci0) ? qb0 + q0 : qb0;
        qb1 = (cr == ci1) ? qb1 + q1 : qb1;
    }
    float P0t  = __shfl_xor(P0, 32);
    float P1t  = __shfl_xor(P1, 32);
    float qb0t = __shfl_xor(qb0, 32);
    float qb1t = __shfl_xor(qb1, 32);
    // out_i = exp(qb_tot) * sum_c exp(-q[c]) * W2[ci][c]
    float ov = (kg == 0) ? __expf(qb0 + qb0t) * (P0 + P0t)
                         : __expf(qb1 + qb1t) * (P1 + P1t);
    float val = __logf(1.0f + ov) * (1.0f / (float)NS);

    for (int off = 32; off; off >>= 1) val += __shfl_down(val, off);
    if (lane == 0) red[w] = val;
    __syncthreads();
    if (tid == 0) atomicAdd(out, red[0] + red[1] + red[2] + red[3]);
}

extern "C" void kernel_launch(void* const* d_in, const int* in_sizes, int n_in,
                              void* d_out, int out_size, void* d_ws, size_t ws_size,
                              hipStream_t stream) {
    const float* ft    = (const float*)d_in[0];
    const float* mean  = (const float*)d_in[1];
    const float* sigma = (const float*)d_in[2];
    const float* cp    = (const float*)d_in[3];
    const int*   ygt   = (const int*)d_in[4];
    float* ws = (float*)d_ws;

    hipMemsetAsync(d_out, 0, sizeof(float), stream);
    precomp_kernel<<<32, 128, 0, stream>>>(mean, sigma, ws);
    gmm_main_kernel<<<NS / 256, 256, 0, stream>>>(ft, ygt, cp, ws, (float*)d_out);
}

// Round 5
// 362.758 us; speedup vs baseline: 1.0865x; 1.0117x over previous
//
#include <hip/hip_runtime.h>
#include <hip/hip_bf16.h>
#include <math.h>

// Problem constants: N=524288, F=128, C=32, EPS=10.0
#define NS 524288
#define FDIM 128
#define CDIM 32
#define EPSV 10.0f

typedef __attribute__((ext_vector_type(8))) short short8;
typedef __attribute__((ext_vector_type(16))) float float16v;

// ws float-index layout:
// [0,4096)    : class table bf16, t-major. 16B unit (f4,c) at unit index f4*32+c,
//               f4 = f>>2 in [0,32). Unit dword j (=f&3) = (bf16(a) | bf16(-b)<<16)
//               for f = f4*4+j, a = 1/(2*sig^2), b = mean/sig^2.
// [4096,4128) : d[c] = sum_f mean^2 * a
// [4128,4160) : L[c] = sum_f log(sig)
#define WS_D 4096
#define WS_L 4128

static __device__ __forceinline__ short f2bf(float x) {
    __hip_bfloat16 h = __float2bfloat16(x);   // RN
    return __builtin_bit_cast(short, h);
}

static __device__ __forceinline__ short8 make_afrag(float4 v) {
    // packed-K interleave: even k -> ft^2 (pairs with a), odd k -> ft (pairs with -b)
    short8 r;
    r[0] = f2bf(v.x * v.x); r[1] = f2bf(v.x);
    r[2] = f2bf(v.y * v.y); r[3] = f2bf(v.y);
    r[4] = f2bf(v.z * v.z); r[5] = f2bf(v.z);
    r[6] = f2bf(v.w * v.w); r[7] = f2bf(v.w);
    return r;
}

__global__ void precomp_kernel(const float* __restrict__ mean,
                               const float* __restrict__ sigma,
                               float* __restrict__ ws) {
    int c = blockIdx.x;   // 32 blocks
    int f = threadIdx.x;  // 128 threads
    float sg  = sigma[c * FDIM + f] + EPSV;
    float m   = mean[c * FDIM + f];
    float inv = 1.0f / (sg * sg);
    float a   = 0.5f * inv;
    float b   = m * inv;
    unsigned ha = (unsigned short)f2bf(a);
    unsigned hb = (unsigned short)f2bf(-b);
    // t-major: unit (f4=f>>2)*32 + c, dword j = f&3
    ((unsigned*)ws)[(((f >> 2) * 32 + c) << 2) + (f & 3)] = ha | (hb << 16);

    float dpart = m * m * a;
    float lpart = __logf(sg);
    for (int off = 32; off; off >>= 1) {
        dpart += __shfl_down(dpart, off);
        lpart += __shfl_down(lpart, off);
    }
    __shared__ float sd[2], sl[2];
    int wv = f >> 6;
    if ((f & 63) == 0) { sd[wv] = dpart; sl[wv] = lpart; }
    __syncthreads();
    if (f == 0) {
        ws[WS_D + c] = sd[0] + sd[1];
        ws[WS_L + c] = sl[0] + sl[1];
    }
}

__launch_bounds__(256)
__global__ void gmm_main_kernel(const float* __restrict__ ft,
                                const int* __restrict__ ygt,
                                const float* __restrict__ cp,
                                const float* __restrict__ ws,
                                float* __restrict__ out) {
    __shared__ short8 Ctab[1024];    // class table, 16 KB (block-shared, LDS-hot)
    __shared__ short8 Astage[2048];  // 4 waves x 512-unit private staging, 32 KB
    __shared__ float  Wp[1024];      // W2[ci][o] = W[ci][o]*exp(d[ci]-d[o])
    __shared__ float  red[4];
    // total 52.1 KB -> 3 blocks/CU, 12 independent waves

    const int tid  = threadIdx.x;
    const int lane = tid & 63;
    const int w    = tid >> 6;      // wave 0..3
    const int n    = lane & 31;     // MFMA: class row (A) / sample col (B,D)
    const int kg   = lane >> 5;     // k half
    const long long bs = (long long)blockIdx.x * 256;

    // ---- per-wave slab: rows bs + w*64 + [0,64), 32 KB contiguous ----
    const int rl = lane >> 3;       // row-in-group 0..7
    const int fq = lane & 7;        // float4-in-quarter 0..7
    const float4* sb = (const float4*)(ft + (bs + w * 64) * FDIM) + rl * 32 + fq;

    // prefetch stage q=0 (8 x 1KB coalesced full-line wave loads)
    float4 va[8], vb[8];
    #pragma unroll
    for (int it = 0; it < 8; ++it) va[it] = sb[it * 256];

    // ---- cooperative setup: class table -> LDS, Wp table ----
    {
        const short8* src = (const short8*)ws;
        #pragma unroll
        for (int u = 0; u < 4; ++u) Ctab[tid + u * 256] = src[tid + u * 256];
    }
    for (int idx = tid; idx < 1024; idx += 256) {
        int ci = idx >> 5, o = idx & 31;
        float val = 0.0f;
        if (ci != o)
            val = __expf(ws[WS_L + ci] - ws[WS_L + o] + ws[WS_D + ci] - ws[WS_D + o])
                  * cp[o] / cp[ci];
        Wp[idx] = val;
    }
    __syncthreads();   // the ONLY barrier before the epilogue

    short8* ast = &Astage[w * 512];
    float16v acc0 = {}, acc1 = {};

    // ---- barrier-free main loop: 4 stages of (8KB stage + 4 k-steps) ----
    #pragma unroll
    for (int q = 0; q < 4; ++q) {
        float4* cur = (q & 1) ? vb : va;
        float4* nxt = (q & 1) ? va : vb;
        if (q < 3) {   // issue next stage's loads BEFORE consuming cur -> vmcnt(8) waits
            #pragma unroll
            for (int it = 0; it < 8; ++it) nxt[it] = sb[it * 256 + (q + 1) * 8];
        }
        // convert + swizzled private-LDS write (row ^ f4 breaks the stride-64 conflict)
        #pragma unroll
        for (int it = 0; it < 8; ++it) {
            int row = it * 8 + rl;
            ast[fq * 64 + (row ^ fq)] = make_afrag(cur[it]);
        }
        // 4 k-steps: class frag from block LDS, sample frags from private LDS
        #pragma unroll
        for (int tl = 0; tl < 4; ++tl) {
            int f4h = 2 * tl + kg;          // within-quarter f4
            short8 cf  = Ctab[(q * 8 + f4h) * 32 + n];
            short8 sf0 = ast[f4h * 64 + (n ^ f4h)];
            short8 sf1 = ast[f4h * 64 + ((32 + n) ^ f4h)];
            acc0 = __builtin_amdgcn_mfma_f32_32x32x16_bf16(cf, sf0, acc0, 0, 0, 0);
            acc1 = __builtin_amdgcn_mfma_f32_32x32x16_bf16(cf, sf1, acc1, 0, 0, 0);
        }
    }

    // ---- in-register epilogue (identical math to R4, which verified) ----
    // D[class][sample]: lane holds sample n (acc0: row w*64+n; acc1: +32),
    // classes cr = (r&3)+8*(r>>2)+4*kg (16 of 32; partner lane^32 has the rest).
    const int ci0 = ygt[bs + w * 64 + n];
    const int ci1 = ygt[bs + w * 64 + 32 + n];
    float P0 = 0.0f, P1 = 0.0f, qb0 = 0.0f, qb1 = 0.0f;
    #pragma unroll
    for (int r = 0; r < 16; ++r) {
        int cr = (r & 3) + 8 * (r >> 2) + 4 * kg;
        float q0 = acc0[r];
        float q1 = acc1[r];
        P0 += __expf(-q0) * Wp[ci0 * 32 + cr];   // diagonal W=0 handles cr==ci
        P1 += __expf(-q1) * Wp[ci1 * 32 + cr];
        qb0 = (cr == ci0) ? qb0 + q0 : qb0;
        qb1 = (cr == ci1) ? qb1 + q1 : qb1;
    }
    float P0t  = __shfl_xor(P0, 32);
    float P1t  = __shfl_xor(P1, 32);
    float qb0t = __shfl_xor(qb0, 32);
    float qb1t = __shfl_xor(qb1, 32);
    float ov = (kg == 0) ? __expf(qb0 + qb0t) * (P0 + P0t)
                         : __expf(qb1 + qb1t) * (P1 + P1t);
    float val = __logf(1.0f + ov) * (1.0f / (float)NS);

    for (int off = 32; off; off >>= 1) val += __shfl_down(val, off);
    if (lane == 0) red[w] = val;
    __syncthreads();
    if (tid == 0) atomicAdd(out, red[0] + red[1] + red[2] + red[3]);
}

extern "C" void kernel_launch(void* const* d_in, const int* in_sizes, int n_in,
                              void* d_out, int out_size, void* d_ws, size_t ws_size,
                              hipStream_t stream) {
    const float* ft    = (const float*)d_in[0];
    const float* mean  = (const float*)d_in[1];
    const float* sigma = (const float*)d_in[2];
    const float* cp    = (const float*)d_in[3];
    const int*   ygt   = (const int*)d_in[4];
    float* ws = (float*)d_ws;

    hipMemsetAsync(d_out, 0, sizeof(float), stream);
    precomp_kernel<<<32, 128, 0, stream>>>(mean, sigma, ws);
    gmm_main_kernel<<<NS / 256, 256, 0, stream>>>(ft, ygt, cp, ws, (float*)d_out);
}